// Round 10
// baseline (1152.291 us; speedup 1.0000x reference)
//
#include <hip/hip_runtime.h>
#include <hip/hip_bf16.h>

// SNU network: 4 layers, B=256, T=100, N_IN=784, N_MID=1024, N_OUT=10, tau=0.8
// Activations b-major: row m = b*TP + t (TP=112 pad). Each fused-GEMM block
// computes a 112x256 tile = ALL t for one (b, n-block), runs the SNU
// recurrence in LDS and writes Y fp8 directly.
//
// R10: residency fix. LDS 52224 -> 30720 so all 4 blocks/CU are co-resident
// (was 3-resident + 1-block straggler round = 2 rounds; matches MfmaUtil
// 29%/10% -> avg 17%). B staged in 128-row halves (16KB buffer reused);
// A-fragments held in registers across both halves; epilogue/recurrence in
// two 128-n phases (Zs[128][102] = 26KB). 4 barriers/K-tile, overlapped by
// 4-resident blocks. __launch_bounds__(256,5).
// prep_fused / layer4_fused / loss_kernel = R9 verbatim.

#define BDIM 256
#define TT   100
#define TP   112         // T padded to 7*16
#define BB   256
#define MM2  (BB * TP)   // 28672 rows
#define NMID 1024
#define K1   784
#define K1P  896         // 784 padded to 7*128
#define NOUT 10
#define N4P  16          // layer-4 N padded
#define L_TAU 0.8f

#define NBLK 256         // block N-tile
#define ZST  102         // Zs stride in shorts (odd dword stride -> no bank conflicts)

// prep_fused block-range map
#define PB_CX   1024                 // convert_x: (b, t-quarter)
#define PB_TC1  (PB_CX + 896)        // W1 transpose: 28 x 32
#define PB_TC23 (PB_TC1 + 2048)     // W2/W3 transpose: 32 x 32 x 2
#define PB_W4   (PB_TC23 + 16)       // convert_w4: 16

typedef __attribute__((ext_vector_type(4))) int   int4x;
typedef __attribute__((ext_vector_type(8))) int   int8x;
typedef __attribute__((ext_vector_type(4))) float f32x4;

__device__ __forceinline__ void async_copy16(const void* g, void* l) {
    __builtin_amdgcn_global_load_lds(
        (const __attribute__((address_space(1))) unsigned int*)g,
        (__attribute__((address_space(3))) unsigned int*)l,
        16, 0, 0);
}

__device__ __forceinline__ unsigned short f2bf(float f) {
    __hip_bfloat16 h = __float2bfloat16(f);
    return __builtin_bit_cast(unsigned short, h);
}
__device__ __forceinline__ float bf2f(unsigned short u) {
    return __uint_as_float((unsigned)u << 16);
}

// ---- W f32 [K,N] -> WT fp8 [N,Kpad], zero-pad k>=K (one 32x32 tile) --------
__device__ __forceinline__ void tc_body(const float* __restrict__ W,
                                        unsigned char* __restrict__ WT,
                                        int K, int N, int Kpad,
                                        int bx, int by, int tidx) {
    __shared__ float tile[32][33];
    int k0 = bx * 32;
    int n0 = by * 32;
    int tx = tidx & 31, ty = tidx >> 5;   // 256 threads: ty=0..7
    #pragma unroll
    for (int i = 0; i < 4; ++i) {
        int k = k0 + ty + i * 8;
        tile[ty + i * 8][tx] = (k < K) ? W[(long)k * N + n0 + tx] : 0.0f;
    }
    __syncthreads();
    int nl = tidx >> 3, kq = tidx & 7;    // n-local 0..31, k-quad 0..7
    int pk = __builtin_amdgcn_cvt_pk_fp8_f32(tile[kq * 4 + 0][nl], tile[kq * 4 + 1][nl], 0, false);
    pk     = __builtin_amdgcn_cvt_pk_fp8_f32(tile[kq * 4 + 2][nl], tile[kq * 4 + 3][nl], pk, true);
    *(int*)(WT + (long)(n0 + nl) * Kpad + k0 + kq * 4) = pk;
}

// ---- ALL prep in one dispatch (branches are block-uniform) -----------------
__global__ __launch_bounds__(256) void prep_fused(
    const float* __restrict__ X,  unsigned char* __restrict__ XB,
    const float* __restrict__ W1, unsigned char* __restrict__ W1T,
    const float* __restrict__ W2, unsigned char* __restrict__ W2T,
    const float* __restrict__ W3, unsigned char* __restrict__ W3T,
    const float* __restrict__ W4, unsigned char* __restrict__ W4T)
{
    const int bid = blockIdx.x;
    const int th  = threadIdx.x;

    if (bid < PB_CX) {
        // X f32 [B][T][784] -> fp8 [b*TP+t][896]; block = (b, quarter of 25 t)
        int b = bid >> 2;
        int q = bid & 3;
        if (th >= K1P / 4) return;       // 224 active
        const float4* xs = (const float4*)(X + ((long)b * TT + q * 25) * K1);
        unsigned char* xd = XB + ((long)b * TP + q * 25) * K1P;
        for (int tt = 0; tt < 25; ++tt) {
            int pk = 0;
            if (th < K1 / 4) {           // 196 threads cover cols 0..783
                float4 v = xs[(long)tt * (K1 / 4) + th];
                pk = __builtin_amdgcn_cvt_pk_fp8_f32(v.x, v.y, 0, false);
                pk = __builtin_amdgcn_cvt_pk_fp8_f32(v.z, v.w, pk, true);
            }
            *(int*)(xd + (long)tt * K1P + th * 4) = pk;
        }
    } else if (bid < PB_TC1) {
        int idx = bid - PB_CX;           // 0..895
        tc_body(W1, W1T, K1, NMID, K1P, idx % 28, idx / 28, th);
    } else if (bid < PB_TC23) {
        int idx = bid - PB_TC1;          // 0..2047
        int z   = idx >> 10;
        int rem = idx & 1023;
        tc_body(z ? W3 : W2, z ? W3T : W2T, NMID, NMID, NMID,
                rem & 31, rem >> 5, th);
    } else {
        // W4 f32 [1024,10] -> fp8 [16][1024]
        int idx = bid - PB_TC23;         // 0..15
        int tid = idx * BDIM + th;
        int n = tid >> 8;
        int k4 = (tid & 255) * 4;
        float v0 = 0, v1 = 0, v2 = 0, v3 = 0;
        if (n < NOUT) {
            v0 = W4[(k4 + 0) * NOUT + n];
            v1 = W4[(k4 + 1) * NOUT + n];
            v2 = W4[(k4 + 2) * NOUT + n];
            v3 = W4[(k4 + 3) * NOUT + n];
        }
        int pk = __builtin_amdgcn_cvt_pk_fp8_f32(v0, v1, 0, false);
        pk     = __builtin_amdgcn_cvt_pk_fp8_f32(v2, v3, pk, true);
        *(int*)(W4T + (long)n * NMID + k4) = pk;
    }
}

// ---- Fused GEMM + SNU recurrence (R10: 30KB LDS, B-half staging) -----------
__global__ __launch_bounds__(256, 5) void gemm_snu_fused(
    const unsigned char* __restrict__ A,    // [MM2, Kp] fp8 (b-major rows)
    const unsigned char* __restrict__ BT,   // [NMID, Kp] fp8
    const float* __restrict__ bias,         // [NMID]
    unsigned char* __restrict__ Y,          // [MM2, NMID] fp8 (b-major rows)
    int Kp)
{
    __shared__ unsigned char smem[30720];        // A 14336 + Bhalf 16384; Zs 26112
    unsigned char* As = smem;                    // [112][128]
    unsigned char* Bs = smem + 14336;            // [128][128] (half panel)
    unsigned short* Zs = (unsigned short*)smem;  // [128][ZST] bf16, n-major

    const int tid  = threadIdx.x;
    const int wave = tid >> 6;
    const int lane = tid & 63;

    // XCD swizzle: 32 b's x 4 n-blocks per XCD -> A strips stay L2-local
    const int l   = blockIdx.x;
    const int xcd = l & 7;
    const int p   = l >> 3;                 // 0..127
    const int b   = xcd * 32 + (p >> 2);
    const int bn  = (p & 3) * NBLK;

    const long arow0 = (long)b * TP;

    // hoist tail operands (HBM latency hidden under GEMM)
    const int ntl = bn + (tid & 127);
    const float bvlo = bias[ntl];
    const float bvhi = bias[ntl + 128];
    unsigned char* ypl = Y + arow0 * NMID + ntl;
    unsigned char* yph = ypl + 128;

    f32x4 acc[7][4] = {};                   // [i][2*h + jj]

    const int srow = tid >> 3;              // 0..31
    const int lch  = tid & 7;
    const int gch  = lch ^ (srow & 7);
    const unsigned char* Aptr = A  + (arow0 + srow) * Kp + gch * 16;
    const unsigned char* Bptr = BT + (long)(bn + srow) * Kp + gch * 16;

    const int mrow = lane & 15;
    const int g    = lane >> 4;             // K-group / n-reg group
    const int wc2  = wave * 32;             // wave's column offset within a half

    for (int k0 = 0; k0 < Kp; k0 += 128) {
        // ---- stage A + B-lo -----------------------------------------------
        #pragma unroll
        for (int i = 0; i < 4; ++i)
            if (srow + i * 32 < TP)
                async_copy16(Aptr + (long)(i * 32) * Kp + k0,
                             &As[(srow + i * 32) * 128 + lch * 16]);
        #pragma unroll
        for (int i = 0; i < 4; ++i)
            async_copy16(Bptr + (long)(i * 32) * Kp + k0,
                         &Bs[(srow + i * 32) * 128 + lch * 16]);
        __syncthreads();

        // A fragments, held in regs for both halves
        int8x af[7];
        #pragma unroll
        for (int i = 0; i < 7; ++i) {
            int row = i * 16 + mrow;
            int r7  = row & 7;
            int4x lo = *(const int4x*)&As[row * 128 + ((2 * g    ) ^ r7) * 16];
            int4x hi = *(const int4x*)&As[row * 128 + ((2 * g + 1) ^ r7) * 16];
            af[i][0] = lo[0]; af[i][1] = lo[1]; af[i][2] = lo[2]; af[i][3] = lo[3];
            af[i][4] = hi[0]; af[i][5] = hi[1]; af[i][6] = hi[2]; af[i][7] = hi[3];
        }

        // ---- half 0: B rows 0..127 ----------------------------------------
        int8x bfr[2];
        #pragma unroll
        for (int jj = 0; jj < 2; ++jj) {
            int row = wc2 + jj * 16 + mrow;
            int r7  = row & 7;
            int4x lo = *(const int4x*)&Bs[row * 128 + ((2 * g    ) ^ r7) * 16];
            int4x hi = *(const int4x*)&Bs[row * 128 + ((2 * g + 1) ^ r7) * 16];
            bfr[jj][0] = lo[0]; bfr[jj][1] = lo[1]; bfr[jj][2] = lo[2]; bfr[jj][3] = lo[3];
            bfr[jj][4] = hi[0]; bfr[jj][5] = hi[1]; bfr[jj][6] = hi[2]; bfr[jj][7] = hi[3];
        }
        #pragma unroll
        for (int i = 0; i < 7; ++i)
            #pragma unroll
            for (int jj = 0; jj < 2; ++jj)
                acc[i][jj] = __builtin_amdgcn_mfma_scale_f32_16x16x128_f8f6f4(
                    bfr[jj], af[i], acc[i][jj],
                    0, 0, 0, 0x7F, 0, 0x7F);
        __syncthreads();                     // all waves done reading B-lo

        // ---- stage B-hi (overwrites Bs) -----------------------------------
        #pragma unroll
        for (int i = 0; i < 4; ++i)
            async_copy16(Bptr + (long)(128 + i * 32) * Kp + k0,
                         &Bs[(srow + i * 32) * 128 + lch * 16]);
        __syncthreads();

        // ---- half 1: B rows 128..255 --------------------------------------
        #pragma unroll
        for (int jj = 0; jj < 2; ++jj) {
            int row = wc2 + jj * 16 + mrow;
            int r7  = row & 7;
            int4x lo = *(const int4x*)&Bs[row * 128 + ((2 * g    ) ^ r7) * 16];
            int4x hi = *(const int4x*)&Bs[row * 128 + ((2 * g + 1) ^ r7) * 16];
            bfr[jj][0] = lo[0]; bfr[jj][1] = lo[1]; bfr[jj][2] = lo[2]; bfr[jj][3] = lo[3];
            bfr[jj][4] = hi[0]; bfr[jj][5] = hi[1]; bfr[jj][6] = hi[2]; bfr[jj][7] = hi[3];
        }
        #pragma unroll
        for (int i = 0; i < 7; ++i)
            #pragma unroll
            for (int jj = 0; jj < 2; ++jj)
                acc[i][2 + jj] = __builtin_amdgcn_mfma_scale_f32_16x16x128_f8f6f4(
                    bfr[jj], af[i], acc[i][2 + jj],
                    0, 0, 0, 0x7F, 0, 0x7F);
        __syncthreads();                     // done reading As + Bs before next stage
    }

    // ---- epilogue + recurrence, two 128-n phases --------------------------
    #pragma unroll
    for (int h = 0; h < 2; ++h) {
        #pragma unroll
        for (int i = 0; i < 7; ++i)
            #pragma unroll
            for (int jj = 0; jj < 2; ++jj) {
                int t  = i * 16 + mrow;
                int nn = wc2 + jj * 16 + g * 4;
                if (t < TT)
                    #pragma unroll
                    for (int r = 0; r < 4; ++r)
                        Zs[(nn + r) * ZST + t] = f2bf(acc[i][2 * h + jj][r]);
            }
        __syncthreads();

        if (tid < 128) {
            const float bv = h ? bvhi : bvlo;
            unsigned char* yp = h ? yph : ypl;
            const unsigned short* zp = Zs + tid * ZST;
            float s = 0.0f, u = 1.0f;        // u = 1 - y
            unsigned int zc = *(const unsigned int*)(zp);
            unsigned int z1 = *(const unsigned int*)(zp + 2);
            for (int t0 = 0; t0 < TT; t0 += 2) {
                unsigned int z2 = 0;
                if (t0 + 4 < TT) z2 = *(const unsigned int*)(zp + t0 + 4);
                float z = bf2f((unsigned short)(zc & 0xFFFFu));
                s = fmaxf(fmaf(L_TAU * s, u, z), 0.0f);
                u = __builtin_amdgcn_rcpf(1.0f + __expf(s + bv));
                yp[(long)t0 * NMID] = (unsigned char)(__builtin_amdgcn_cvt_pk_fp8_f32(1.0f - u, 0.0f, 0, false) & 0xFF);
                z = bf2f((unsigned short)(zc >> 16));
                s = fmaxf(fmaf(L_TAU * s, u, z), 0.0f);
                u = __builtin_amdgcn_rcpf(1.0f + __expf(s + bv));
                yp[(long)(t0 + 1) * NMID] = (unsigned char)(__builtin_amdgcn_cvt_pk_fp8_f32(1.0f - u, 0.0f, 0, false) & 0xFF);
                zc = z1; z1 = z2;
            }
        }
        __syncthreads();                     // Zs reads done before phase-1 overwrite
    }
}

// ---- Layer 4: GEMM (112x16, K=1024) + recurrence + m, one block per b ------
__global__ __launch_bounds__(256) void layer4_fused(
    const unsigned char* __restrict__ Y3,   // [MM2, NMID] fp8
    const unsigned char* __restrict__ W4T,  // [16][1024] fp8
    const float* __restrict__ b4,
    float* __restrict__ m_out)              // [256][10]
{
    __shared__ float Z4s[TP][N4P];          // 7168 B

    const int tid  = threadIdx.x;
    const int wave = tid >> 6;
    const int lane = tid & 63;
    const int mrow = lane & 15;
    const int g    = lane >> 4;
    const int b    = blockIdx.x;

    // W4 fragments once per wave (same for all row-groups)
    int8x wf[8];
    {
        const unsigned char* wp = W4T + (long)mrow * NMID + g * 32;
        #pragma unroll
        for (int kt = 0; kt < 8; ++kt) {
            int4x wlo = *(const int4x*)(wp + kt * 128);
            int4x whi = *(const int4x*)(wp + kt * 128 + 16);
            wf[kt][0] = wlo[0]; wf[kt][1] = wlo[1]; wf[kt][2] = wlo[2]; wf[kt][3] = wlo[3];
            wf[kt][4] = whi[0]; wf[kt][5] = whi[1]; wf[kt][6] = whi[2]; wf[kt][7] = whi[3];
        }
    }

    for (int rg = wave; rg < 7; rg += 4) {   // 7 row-groups of 16 (112 rows)
        const long row = (long)b * TP + rg * 16 + mrow;
        const unsigned char* ap = Y3 + row * NMID + g * 32;
        f32x4 acc = {};
        #pragma unroll
        for (int kt = 0; kt < 8; ++kt) {
            int4x alo = *(const int4x*)(ap + kt * 128);
            int4x ahi = *(const int4x*)(ap + kt * 128 + 16);
            int8x af;
            af[0] = alo[0]; af[1] = alo[1]; af[2] = alo[2]; af[3] = alo[3];
            af[4] = ahi[0]; af[5] = ahi[1]; af[6] = ahi[2]; af[7] = ahi[3];
            acc = __builtin_amdgcn_mfma_scale_f32_16x16x128_f8f6f4(
                wf[kt], af, acc, 0, 0, 0, 0x7F, 0, 0x7F);
        }
        *(f32x4*)&Z4s[rg * 16 + mrow][g * 4] = acc;
    }
    __syncthreads();

    if (tid < NOUT) {
        const float bv = b4[tid];
        float s = 0.0f, u = 1.0f, msum = 0.0f;
        float zc = Z4s[0][tid];
        float z1 = Z4s[1][tid];
        for (int t = 0; t < TT; ++t) {
            float z2 = (t + 2 < TT) ? Z4s[t + 2][tid] : 0.0f;
            s = fmaxf(fmaf(L_TAU * s, u, zc), 0.0f);
            u = __builtin_amdgcn_rcpf(1.0f + __expf(s + bv));
            msum += 1.0f - u;
            zc = z1; z1 = z2;
        }
        m_out[b * NOUT + tid] = msum;
    }
}

// ---- loss = -mean_b log_softmax(m)[b, y[b]] --------------------------------
__global__ void loss_kernel(const float* __restrict__ m, const int* __restrict__ y,
                            float* __restrict__ out) {
    __shared__ float red[BDIM];
    int b = threadIdx.x;   // 256 threads, 1 block
    float v[NOUT];
    float mx = -1e30f;
    #pragma unroll
    for (int n = 0; n < NOUT; ++n) { v[n] = m[b * NOUT + n]; mx = fmaxf(mx, v[n]); }
    float se = 0.0f;
    #pragma unroll
    for (int n = 0; n < NOUT; ++n) se += __expf(v[n] - mx);
    float lse = mx + __logf(se);
    int lbl = y[b];
    float vy = 0.0f;
    #pragma unroll
    for (int n = 0; n < NOUT; ++n) if (n == lbl) vy = v[n];
    red[b] = -(vy - lse);
    __syncthreads();
    for (int off = 128; off; off >>= 1) {
        if (b < off) red[b] += red[b + off];
        __syncthreads();
    }
    if (b == 0) out[0] = red[0] / (float)BB;
}

extern "C" void kernel_launch(void* const* d_in, const int* in_sizes, int n_in,
                              void* d_out, int out_size, void* d_ws, size_t ws_size,
                              hipStream_t stream) {
    const float* x  = (const float*)d_in[0];
    const int*   y  = (const int*)  d_in[1];
    const float* W1 = (const float*)d_in[2];
    const float* b1 = (const float*)d_in[3];
    const float* W2 = (const float*)d_in[4];
    const float* b2 = (const float*)d_in[5];
    const float* W3 = (const float*)d_in[6];
    const float* b3 = (const float*)d_in[7];
    const float* W4 = (const float*)d_in[8];
    const float* b4 = (const float*)d_in[9];
    float* out = (float*)d_out;

    char* ws = (char*)d_ws;
    size_t off = 0;
    auto alloc = [&](size_t bytes) {
        char* p = ws + off;
        off = (off + bytes + 255) & ~(size_t)255;
        return (void*)p;
    };
    unsigned char* XB  = (unsigned char*)alloc((size_t)MM2 * K1P);
    unsigned char* W1T = (unsigned char*)alloc((size_t)NMID * K1P);
    unsigned char* W2T = (unsigned char*)alloc((size_t)NMID * NMID);
    unsigned char* W3T = (unsigned char*)alloc((size_t)NMID * NMID);
    unsigned char* W4T = (unsigned char*)alloc((size_t)N4P * NMID);
    unsigned char* Ya  = (unsigned char*)alloc((size_t)MM2 * NMID);
    unsigned char* Yb  = (unsigned char*)alloc((size_t)MM2 * NMID);

    // one prep dispatch (all converts independent)
    prep_fused<<<PB_W4, BDIM, 0, stream>>>(x, XB, W1, W1T, W2, W2T, W3, W3T, W4, W4T);

    const int fblocks = BB * (NMID / NBLK);   // 1024
    gemm_snu_fused<<<fblocks, BDIM, 0, stream>>>(XB, W1T, b1, Ya, K1P);
    gemm_snu_fused<<<fblocks, BDIM, 0, stream>>>(Ya, W2T, b2, Yb, NMID);
    gemm_snu_fused<<<fblocks, BDIM, 0, stream>>>(Yb, W3T, b3, Ya, NMID);
    layer4_fused<<<BB, BDIM, 0, stream>>>(Ya, W4T, b4, out + 1);
    loss_kernel<<<1, BDIM, 0, stream>>>(out + 1, y, out);
}

// Round 11
// 299.249 us; speedup vs baseline: 3.8506x; 3.8506x over previous
//
#include <hip/hip_runtime.h>
#include <hip/hip_bf16.h>

// SNU network: 4 layers, B=256, T=100, N_IN=784, N_MID=1024, N_OUT=10, tau=0.8
// Activations b-major: row m = b*TP + t (TP=112 pad). Each fused-GEMM block
// computes a 112x256 tile = ALL t for one (b, n-block), runs the SNU
// recurrence in LDS (bf16 Zs[n][t]) and writes Y fp8 directly.
//
// R11: R9 GEMM (best, 66us; R10's 30KB/launch_bounds(5) variant SPILLED --
// VGPR 48, 1.4GB scratch traffic) + K-phase rotation: odd-parity blocks
// visit K-tiles in rotated order (roff = NT/2). Theory: co-resident blocks
// are phase-locked (stage/drain/compute bursts align -> m114 overlap never
// engages; explains why all schedule variants were null). Rotation
// interleaves one block's stage with the other's compute. K-order is
// mathematically irrelevant (accumulation commutes; reorder noise << fp8
// quantization).

#define BDIM 256
#define TT   100
#define TP   112         // T padded to 7*16
#define BB   256
#define MM2  (BB * TP)   // 28672 rows
#define NMID 1024
#define K1   784
#define K1P  896         // 784 padded to 7*128
#define NOUT 10
#define N4P  16          // layer-4 N padded
#define L_TAU 0.8f

#define NBLK 256         // block N-tile
#define ZST  102         // Zs stride in shorts (odd dword stride -> no bank conflicts)

// prep_fused block-range map
#define PB_CX   1024                 // convert_x: (b, t-quarter)
#define PB_TC1  (PB_CX + 896)        // W1 transpose: 28 x 32
#define PB_TC23 (PB_TC1 + 2048)     // W2/W3 transpose: 32 x 32 x 2
#define PB_W4   (PB_TC23 + 16)       // convert_w4: 16

typedef __attribute__((ext_vector_type(4))) int   int4x;
typedef __attribute__((ext_vector_type(8))) int   int8x;
typedef __attribute__((ext_vector_type(4))) float f32x4;

__device__ __forceinline__ void async_copy16(const void* g, void* l) {
    __builtin_amdgcn_global_load_lds(
        (const __attribute__((address_space(1))) unsigned int*)g,
        (__attribute__((address_space(3))) unsigned int*)l,
        16, 0, 0);
}

__device__ __forceinline__ unsigned short f2bf(float f) {
    __hip_bfloat16 h = __float2bfloat16(f);
    return __builtin_bit_cast(unsigned short, h);
}
__device__ __forceinline__ float bf2f(unsigned short u) {
    return __uint_as_float((unsigned)u << 16);
}

// ---- W f32 [K,N] -> WT fp8 [N,Kpad], zero-pad k>=K (one 32x32 tile) --------
__device__ __forceinline__ void tc_body(const float* __restrict__ W,
                                        unsigned char* __restrict__ WT,
                                        int K, int N, int Kpad,
                                        int bx, int by, int tidx) {
    __shared__ float tile[32][33];
    int k0 = bx * 32;
    int n0 = by * 32;
    int tx = tidx & 31, ty = tidx >> 5;   // 256 threads: ty=0..7
    #pragma unroll
    for (int i = 0; i < 4; ++i) {
        int k = k0 + ty + i * 8;
        tile[ty + i * 8][tx] = (k < K) ? W[(long)k * N + n0 + tx] : 0.0f;
    }
    __syncthreads();
    int nl = tidx >> 3, kq = tidx & 7;    // n-local 0..31, k-quad 0..7
    int pk = __builtin_amdgcn_cvt_pk_fp8_f32(tile[kq * 4 + 0][nl], tile[kq * 4 + 1][nl], 0, false);
    pk     = __builtin_amdgcn_cvt_pk_fp8_f32(tile[kq * 4 + 2][nl], tile[kq * 4 + 3][nl], pk, true);
    *(int*)(WT + (long)(n0 + nl) * Kpad + k0 + kq * 4) = pk;
}

// ---- ALL prep in one dispatch (branches are block-uniform) -----------------
__global__ __launch_bounds__(256) void prep_fused(
    const float* __restrict__ X,  unsigned char* __restrict__ XB,
    const float* __restrict__ W1, unsigned char* __restrict__ W1T,
    const float* __restrict__ W2, unsigned char* __restrict__ W2T,
    const float* __restrict__ W3, unsigned char* __restrict__ W3T,
    const float* __restrict__ W4, unsigned char* __restrict__ W4T)
{
    const int bid = blockIdx.x;
    const int th  = threadIdx.x;

    if (bid < PB_CX) {
        // X f32 [B][T][784] -> fp8 [b*TP+t][896]; block = (b, quarter of 25 t)
        int b = bid >> 2;
        int q = bid & 3;
        if (th >= K1P / 4) return;       // 224 active
        const float4* xs = (const float4*)(X + ((long)b * TT + q * 25) * K1);
        unsigned char* xd = XB + ((long)b * TP + q * 25) * K1P;
        for (int tt = 0; tt < 25; ++tt) {
            int pk = 0;
            if (th < K1 / 4) {           // 196 threads cover cols 0..783
                float4 v = xs[(long)tt * (K1 / 4) + th];
                pk = __builtin_amdgcn_cvt_pk_fp8_f32(v.x, v.y, 0, false);
                pk = __builtin_amdgcn_cvt_pk_fp8_f32(v.z, v.w, pk, true);
            }
            *(int*)(xd + (long)tt * K1P + th * 4) = pk;
        }
    } else if (bid < PB_TC1) {
        int idx = bid - PB_CX;           // 0..895
        tc_body(W1, W1T, K1, NMID, K1P, idx % 28, idx / 28, th);
    } else if (bid < PB_TC23) {
        int idx = bid - PB_TC1;          // 0..2047
        int z   = idx >> 10;
        int rem = idx & 1023;
        tc_body(z ? W3 : W2, z ? W3T : W2T, NMID, NMID, NMID,
                rem & 31, rem >> 5, th);
    } else {
        // W4 f32 [1024,10] -> fp8 [16][1024]
        int idx = bid - PB_TC23;         // 0..15
        int tid = idx * BDIM + th;
        int n = tid >> 8;
        int k4 = (tid & 255) * 4;
        float v0 = 0, v1 = 0, v2 = 0, v3 = 0;
        if (n < NOUT) {
            v0 = W4[(k4 + 0) * NOUT + n];
            v1 = W4[(k4 + 1) * NOUT + n];
            v2 = W4[(k4 + 2) * NOUT + n];
            v3 = W4[(k4 + 3) * NOUT + n];
        }
        int pk = __builtin_amdgcn_cvt_pk_fp8_f32(v0, v1, 0, false);
        pk     = __builtin_amdgcn_cvt_pk_fp8_f32(v2, v3, pk, true);
        *(int*)(W4T + (long)n * NMID + k4) = pk;
    }
}

// ---- staging: A strip (112 rows) + B strip (256 rows) for one K-tile -------
__device__ __forceinline__ void stage_tile(const unsigned char* Aptr,
                                           const unsigned char* Bptr,
                                           unsigned char* As, unsigned char* Bs,
                                           int srow, int lch, int Kp, int k0) {
    #pragma unroll
    for (int i = 0; i < 4; ++i)
        if (srow + i * 32 < TP)          // A: 112 rows (3.5 staging steps)
            async_copy16(Aptr + (long)(i * 32) * Kp + k0,
                         &As[(srow + i * 32) * 128 + lch * 16]);
    #pragma unroll
    for (int i = 0; i < 8; ++i)          // B: 256 rows
        async_copy16(Bptr + (long)(i * 32) * Kp + k0,
                     &Bs[(srow + i * 32) * 128 + lch * 16]);
}

// ---- Fused GEMM + SNU recurrence (R9 + K-phase rotation) -------------------
__global__ __launch_bounds__(256, 3) void gemm_snu_fused(
    const unsigned char* __restrict__ A,    // [MM2, Kp] fp8 (b-major rows)
    const unsigned char* __restrict__ BT,   // [NMID, Kp] fp8
    const float* __restrict__ bias,         // [NMID]
    unsigned char* __restrict__ Y,          // [MM2, NMID] fp8 (b-major rows)
    int Kp)
{
    __shared__ unsigned char smem[52224];        // max(stage 47104, Zs 52224)
    unsigned char* As = smem;                    // [112][128]
    unsigned char* Bs = smem + 14336;            // [256][128]
    unsigned short* Zs = (unsigned short*)smem;  // [256][ZST] bf16, n-major

    const int tid  = threadIdx.x;
    const int wave = tid >> 6;
    const int lane = tid & 63;

    // XCD swizzle: 32 b's x 4 n-blocks per XCD -> A strips stay L2-local
    const int l   = blockIdx.x;
    const int xcd = l & 7;
    const int p   = l >> 3;                 // 0..127
    const int b   = xcd * 32 + (p >> 2);
    const int bn  = (p & 3) * NBLK;

    const long arow0 = (long)b * TP;

    // hoist tail operands off the critical path (HBM latency hidden under GEMM)
    const float bv = bias[bn + tid];
    unsigned char* yp = Y + arow0 * NMID + bn + tid;

    f32x4 acc[7][4] = {};

    const int srow = tid >> 3;              // 0..31
    const int lch  = tid & 7;
    const int gch  = lch ^ (srow & 7);
    const unsigned char* Aptr = A  + (arow0 + srow) * Kp + gch * 16;
    const unsigned char* Bptr = BT + (long)(bn + srow) * Kp + gch * 16;

    const int mrow = lane & 15;
    const int g    = lane >> 4;             // K-group / n-reg group
    const int wc   = wave * 64;             // wave's column offset

    // K-phase rotation: de-phase co-resident blocks (pair l, l+8 -> p, p+1).
    // K-accumulation order is irrelevant to the result.
    const int NT   = Kp >> 7;
    const int roff = (p & 1) * (NT >> 1);

    for (int tt = 0; tt < NT; ++tt) {
        int kt = tt + roff;
        if (kt >= NT) kt -= NT;
        const int k0 = kt << 7;

        stage_tile(Aptr, Bptr, As, Bs, srow, lch, Kp, k0);
        __syncthreads();

        int8x bfr[4];
        #pragma unroll
        for (int j = 0; j < 4; ++j) {
            int row = wc + j * 16 + mrow;
            int r7  = row & 7;
            int4x lo = *(const int4x*)&Bs[row * 128 + ((2 * g    ) ^ r7) * 16];
            int4x hi = *(const int4x*)&Bs[row * 128 + ((2 * g + 1) ^ r7) * 16];
            bfr[j][0] = lo[0]; bfr[j][1] = lo[1]; bfr[j][2] = lo[2]; bfr[j][3] = lo[3];
            bfr[j][4] = hi[0]; bfr[j][5] = hi[1]; bfr[j][6] = hi[2]; bfr[j][7] = hi[3];
        }
        #pragma unroll
        for (int i = 0; i < 7; ++i) {
            int row = i * 16 + mrow;
            int r7  = row & 7;
            int4x lo = *(const int4x*)&As[row * 128 + ((2 * g    ) ^ r7) * 16];
            int4x hi = *(const int4x*)&As[row * 128 + ((2 * g + 1) ^ r7) * 16];
            int8x af;
            af[0] = lo[0]; af[1] = lo[1]; af[2] = lo[2]; af[3] = lo[3];
            af[4] = hi[0]; af[5] = hi[1]; af[6] = hi[2]; af[7] = hi[3];
            #pragma unroll
            for (int j = 0; j < 4; ++j)
                acc[i][j] = __builtin_amdgcn_mfma_scale_f32_16x16x128_f8f6f4(
                    bfr[j], af, acc[i][j],
                    0, 0,            // cbsz=fp8 e4m3, blgp=fp8 e4m3
                    0, 0x7F,         // unit scale
                    0, 0x7F);
        }
        __syncthreads();
    }

    // epilogue: acc (lane&15 -> t-in-tile, g*4+reg -> n-in-16) -> Zs[n][t] bf16
    #pragma unroll
    for (int i = 0; i < 7; ++i)
        #pragma unroll
        for (int j = 0; j < 4; ++j) {
            int t  = i * 16 + mrow;
            int nn = wc + j * 16 + g * 4;
            if (t < TT)
                #pragma unroll
                for (int r = 0; r < 4; ++r)
                    Zs[(nn + r) * ZST + t] = f2bf(acc[i][j][r]);
        }
    __syncthreads();

    // recurrence: thread n of 256 walks t sequentially, writes Y fp8.
    // distance-2 prefetched ds_read_b32 (2 bf16/read), conflict-free odd-dword
    // stride; chain carries u = 1-y.
    {
        const unsigned short* zp = Zs + tid * ZST;
        float s = 0.0f, u = 1.0f;            // u = 1 - y
        unsigned int zc = *(const unsigned int*)(zp);        // t 0,1
        unsigned int z1 = *(const unsigned int*)(zp + 2);    // t 2,3
        for (int t0 = 0; t0 < TT; t0 += 2) {
            unsigned int z2 = 0;
            if (t0 + 4 < TT) z2 = *(const unsigned int*)(zp + t0 + 4);
            // t0
            float z = bf2f((unsigned short)(zc & 0xFFFFu));
            s = fmaxf(fmaf(L_TAU * s, u, z), 0.0f);
            u = __builtin_amdgcn_rcpf(1.0f + __expf(s + bv));
            yp[(long)t0 * NMID] = (unsigned char)(__builtin_amdgcn_cvt_pk_fp8_f32(1.0f - u, 0.0f, 0, false) & 0xFF);
            // t0+1
            z = bf2f((unsigned short)(zc >> 16));
            s = fmaxf(fmaf(L_TAU * s, u, z), 0.0f);
            u = __builtin_amdgcn_rcpf(1.0f + __expf(s + bv));
            yp[(long)(t0 + 1) * NMID] = (unsigned char)(__builtin_amdgcn_cvt_pk_fp8_f32(1.0f - u, 0.0f, 0, false) & 0xFF);
            zc = z1; z1 = z2;
        }
    }
}

// ---- Layer 4: GEMM (112x16, K=1024) + recurrence + m, one block per b ------
__global__ __launch_bounds__(256) void layer4_fused(
    const unsigned char* __restrict__ Y3,   // [MM2, NMID] fp8
    const unsigned char* __restrict__ W4T,  // [16][1024] fp8
    const float* __restrict__ b4,
    float* __restrict__ m_out)              // [256][10]
{
    __shared__ float Z4s[TP][N4P];          // 7168 B

    const int tid  = threadIdx.x;
    const int wave = tid >> 6;
    const int lane = tid & 63;
    const int mrow = lane & 15;
    const int g    = lane >> 4;
    const int b    = blockIdx.x;

    // W4 fragments once per wave (same for all row-groups)
    int8x wf[8];
    {
        const unsigned char* wp = W4T + (long)mrow * NMID + g * 32;
        #pragma unroll
        for (int kt = 0; kt < 8; ++kt) {
            int4x wlo = *(const int4x*)(wp + kt * 128);
            int4x whi = *(const int4x*)(wp + kt * 128 + 16);
            wf[kt][0] = wlo[0]; wf[kt][1] = wlo[1]; wf[kt][2] = wlo[2]; wf[kt][3] = wlo[3];
            wf[kt][4] = whi[0]; wf[kt][5] = whi[1]; wf[kt][6] = whi[2]; wf[kt][7] = whi[3];
        }
    }

    for (int rg = wave; rg < 7; rg += 4) {   // 7 row-groups of 16 (112 rows)
        const long row = (long)b * TP + rg * 16 + mrow;
        const unsigned char* ap = Y3 + row * NMID + g * 32;
        f32x4 acc = {};
        #pragma unroll
        for (int kt = 0; kt < 8; ++kt) {
            int4x alo = *(const int4x*)(ap + kt * 128);
            int4x ahi = *(const int4x*)(ap + kt * 128 + 16);
            int8x af;
            af[0] = alo[0]; af[1] = alo[1]; af[2] = alo[2]; af[3] = alo[3];
            af[4] = ahi[0]; af[5] = ahi[1]; af[6] = ahi[2]; af[7] = ahi[3];
            acc = __builtin_amdgcn_mfma_scale_f32_16x16x128_f8f6f4(
                wf[kt], af, acc, 0, 0, 0, 0x7F, 0, 0x7F);
        }
        *(f32x4*)&Z4s[rg * 16 + mrow][g * 4] = acc;
    }
    __syncthreads();

    if (tid < NOUT) {
        const float bv = b4[tid];
        float s = 0.0f, u = 1.0f, msum = 0.0f;
        float zc = Z4s[0][tid];
        float z1 = Z4s[1][tid];
        for (int t = 0; t < TT; ++t) {
            float z2 = (t + 2 < TT) ? Z4s[t + 2][tid] : 0.0f;
            s = fmaxf(fmaf(L_TAU * s, u, zc), 0.0f);
            u = __builtin_amdgcn_rcpf(1.0f + __expf(s + bv));
            msum += 1.0f - u;
            zc = z1; z1 = z2;
        }
        m_out[b * NOUT + tid] = msum;
    }
}

// ---- loss = -mean_b log_softmax(m)[b, y[b]] --------------------------------
__global__ void loss_kernel(const float* __restrict__ m, const int* __restrict__ y,
                            float* __restrict__ out) {
    __shared__ float red[BDIM];
    int b = threadIdx.x;   // 256 threads, 1 block
    float v[NOUT];
    float mx = -1e30f;
    #pragma unroll
    for (int n = 0; n < NOUT; ++n) { v[n] = m[b * NOUT + n]; mx = fmaxf(mx, v[n]); }
    float se = 0.0f;
    #pragma unroll
    for (int n = 0; n < NOUT; ++n) se += __expf(v[n] - mx);
    float lse = mx + __logf(se);
    int lbl = y[b];
    float vy = 0.0f;
    #pragma unroll
    for (int n = 0; n < NOUT; ++n) if (n == lbl) vy = v[n];
    red[b] = -(vy - lse);
    __syncthreads();
    for (int off = 128; off; off >>= 1) {
        if (b < off) red[b] += red[b + off];
        __syncthreads();
    }
    if (b == 0) out[0] = red[0] / (float)BB;
}

extern "C" void kernel_launch(void* const* d_in, const int* in_sizes, int n_in,
                              void* d_out, int out_size, void* d_ws, size_t ws_size,
                              hipStream_t stream) {
    const float* x  = (const float*)d_in[0];
    const int*   y  = (const int*)  d_in[1];
    const float* W1 = (const float*)d_in[2];
    const float* b1 = (const float*)d_in[3];
    const float* W2 = (const float*)d_in[4];
    const float* b2 = (const float*)d_in[5];
    const float* W3 = (const float*)d_in[6];
    const float* b3 = (const float*)d_in[7];
    const float* W4 = (const float*)d_in[8];
    const float* b4 = (const float*)d_in[9];
    float* out = (float*)d_out;

    char* ws = (char*)d_ws;
    size_t off = 0;
    auto alloc = [&](size_t bytes) {
        char* p = ws + off;
        off = (off + bytes + 255) & ~(size_t)255;
        return (void*)p;
    };
    unsigned char* XB  = (unsigned char*)alloc((size_t)MM2 * K1P);
    unsigned char* W1T = (unsigned char*)alloc((size_t)NMID * K1P);
    unsigned char* W2T = (unsigned char*)alloc((size_t)NMID * NMID);
    unsigned char* W3T = (unsigned char*)alloc((size_t)NMID * NMID);
    unsigned char* W4T = (unsigned char*)alloc((size_t)N4P * NMID);
    unsigned char* Ya  = (unsigned char*)alloc((size_t)MM2 * NMID);
    unsigned char* Yb  = (unsigned char*)alloc((size_t)MM2 * NMID);

    // one prep dispatch (all converts independent)
    prep_fused<<<PB_W4, BDIM, 0, stream>>>(x, XB, W1, W1T, W2, W2T, W3, W3T, W4, W4T);

    const int fblocks = BB * (NMID / NBLK);   // 1024
    gemm_snu_fused<<<fblocks, BDIM, 0, stream>>>(XB, W1T, b1, Ya, K1P);
    gemm_snu_fused<<<fblocks, BDIM, 0, stream>>>(Ya, W2T, b2, Yb, NMID);
    gemm_snu_fused<<<fblocks, BDIM, 0, stream>>>(Yb, W3T, b3, Ya, NMID);
    layer4_fused<<<BB, BDIM, 0, stream>>>(Ya, W4T, b4, out + 1);
    loss_kernel<<<1, BDIM, 0, stream>>>(out + 1, y, out);
}

// Round 13
// 297.715 us; speedup vs baseline: 3.8704x; 1.0052x over previous
//
#include <hip/hip_runtime.h>
#include <hip/hip_bf16.h>

// SNU network: 4 layers, B=256, T=100, N_IN=784, N_MID=1024, N_OUT=10, tau=0.8
// Activations b-major: row m = b*TP + t (TP=112 pad). Each fused-GEMM block
// computes a 112x256 tile = ALL t for one (b, n-block), runs the SNU
// recurrence in LDS (bf16 Zs[n][t]) and writes Y fp8 directly.
//
// R13 = R12 retry (R12 hit the known infra double-failure mode; change was a
// one-line scalar and cannot plausibly fault -- same pattern as R4/R5 which
// were later exonerated). Full per-block K-phase rotation, now via branchless
// AND+conditional-subtract instead of runtime % (defensive; NT is 7 or 8).
// R11 (2-phase rotation) measured 55.5us/dispatch, MfmaUtil 21; theory says
// full rotation smooths the stage bursts further.

#define BDIM 256
#define TT   100
#define TP   112         // T padded to 7*16
#define BB   256
#define MM2  (BB * TP)   // 28672 rows
#define NMID 1024
#define K1   784
#define K1P  896         // 784 padded to 7*128
#define NOUT 10
#define N4P  16          // layer-4 N padded
#define L_TAU 0.8f

#define NBLK 256         // block N-tile
#define ZST  102         // Zs stride in shorts (odd dword stride -> no bank conflicts)

// prep_fused block-range map
#define PB_CX   1024                 // convert_x: (b, t-quarter)
#define PB_TC1  (PB_CX + 896)        // W1 transpose: 28 x 32
#define PB_TC23 (PB_TC1 + 2048)     // W2/W3 transpose: 32 x 32 x 2
#define PB_W4   (PB_TC23 + 16)       // convert_w4: 16

typedef __attribute__((ext_vector_type(4))) int   int4x;
typedef __attribute__((ext_vector_type(8))) int   int8x;
typedef __attribute__((ext_vector_type(4))) float f32x4;

__device__ __forceinline__ void async_copy16(const void* g, void* l) {
    __builtin_amdgcn_global_load_lds(
        (const __attribute__((address_space(1))) unsigned int*)g,
        (__attribute__((address_space(3))) unsigned int*)l,
        16, 0, 0);
}

__device__ __forceinline__ unsigned short f2bf(float f) {
    __hip_bfloat16 h = __float2bfloat16(f);
    return __builtin_bit_cast(unsigned short, h);
}
__device__ __forceinline__ float bf2f(unsigned short u) {
    return __uint_as_float((unsigned)u << 16);
}

// ---- W f32 [K,N] -> WT fp8 [N,Kpad], zero-pad k>=K (one 32x32 tile) --------
__device__ __forceinline__ void tc_body(const float* __restrict__ W,
                                        unsigned char* __restrict__ WT,
                                        int K, int N, int Kpad,
                                        int bx, int by, int tidx) {
    __shared__ float tile[32][33];
    int k0 = bx * 32;
    int n0 = by * 32;
    int tx = tidx & 31, ty = tidx >> 5;   // 256 threads: ty=0..7
    #pragma unroll
    for (int i = 0; i < 4; ++i) {
        int k = k0 + ty + i * 8;
        tile[ty + i * 8][tx] = (k < K) ? W[(long)k * N + n0 + tx] : 0.0f;
    }
    __syncthreads();
    int nl = tidx >> 3, kq = tidx & 7;    // n-local 0..31, k-quad 0..7
    int pk = __builtin_amdgcn_cvt_pk_fp8_f32(tile[kq * 4 + 0][nl], tile[kq * 4 + 1][nl], 0, false);
    pk     = __builtin_amdgcn_cvt_pk_fp8_f32(tile[kq * 4 + 2][nl], tile[kq * 4 + 3][nl], pk, true);
    *(int*)(WT + (long)(n0 + nl) * Kpad + k0 + kq * 4) = pk;
}

// ---- ALL prep in one dispatch (branches are block-uniform) -----------------
__global__ __launch_bounds__(256) void prep_fused(
    const float* __restrict__ X,  unsigned char* __restrict__ XB,
    const float* __restrict__ W1, unsigned char* __restrict__ W1T,
    const float* __restrict__ W2, unsigned char* __restrict__ W2T,
    const float* __restrict__ W3, unsigned char* __restrict__ W3T,
    const float* __restrict__ W4, unsigned char* __restrict__ W4T)
{
    const int bid = blockIdx.x;
    const int th  = threadIdx.x;

    if (bid < PB_CX) {
        // X f32 [B][T][784] -> fp8 [b*TP+t][896]; block = (b, quarter of 25 t)
        int b = bid >> 2;
        int q = bid & 3;
        if (th >= K1P / 4) return;       // 224 active
        const float4* xs = (const float4*)(X + ((long)b * TT + q * 25) * K1);
        unsigned char* xd = XB + ((long)b * TP + q * 25) * K1P;
        for (int tt = 0; tt < 25; ++tt) {
            int pk = 0;
            if (th < K1 / 4) {           // 196 threads cover cols 0..783
                float4 v = xs[(long)tt * (K1 / 4) + th];
                pk = __builtin_amdgcn_cvt_pk_fp8_f32(v.x, v.y, 0, false);
                pk = __builtin_amdgcn_cvt_pk_fp8_f32(v.z, v.w, pk, true);
            }
            *(int*)(xd + (long)tt * K1P + th * 4) = pk;
        }
    } else if (bid < PB_TC1) {
        int idx = bid - PB_CX;           // 0..895
        tc_body(W1, W1T, K1, NMID, K1P, idx % 28, idx / 28, th);
    } else if (bid < PB_TC23) {
        int idx = bid - PB_TC1;          // 0..2047
        int z   = idx >> 10;
        int rem = idx & 1023;
        tc_body(z ? W3 : W2, z ? W3T : W2T, NMID, NMID, NMID,
                rem & 31, rem >> 5, th);
    } else {
        // W4 f32 [1024,10] -> fp8 [16][1024]
        int idx = bid - PB_TC23;         // 0..15
        int tid = idx * BDIM + th;
        int n = tid >> 8;
        int k4 = (tid & 255) * 4;
        float v0 = 0, v1 = 0, v2 = 0, v3 = 0;
        if (n < NOUT) {
            v0 = W4[(k4 + 0) * NOUT + n];
            v1 = W4[(k4 + 1) * NOUT + n];
            v2 = W4[(k4 + 2) * NOUT + n];
            v3 = W4[(k4 + 3) * NOUT + n];
        }
        int pk = __builtin_amdgcn_cvt_pk_fp8_f32(v0, v1, 0, false);
        pk     = __builtin_amdgcn_cvt_pk_fp8_f32(v2, v3, pk, true);
        *(int*)(W4T + (long)n * NMID + k4) = pk;
    }
}

// ---- staging: A strip (112 rows) + B strip (256 rows) for one K-tile -------
__device__ __forceinline__ void stage_tile(const unsigned char* Aptr,
                                           const unsigned char* Bptr,
                                           unsigned char* As, unsigned char* Bs,
                                           int srow, int lch, int Kp, int k0) {
    #pragma unroll
    for (int i = 0; i < 4; ++i)
        if (srow + i * 32 < TP)          // A: 112 rows (3.5 staging steps)
            async_copy16(Aptr + (long)(i * 32) * Kp + k0,
                         &As[(srow + i * 32) * 128 + lch * 16]);
    #pragma unroll
    for (int i = 0; i < 8; ++i)          // B: 256 rows
        async_copy16(Bptr + (long)(i * 32) * Kp + k0,
                     &Bs[(srow + i * 32) * 128 + lch * 16]);
}

// ---- Fused GEMM + SNU recurrence (full per-block K rotation) ---------------
__global__ __launch_bounds__(256, 3) void gemm_snu_fused(
    const unsigned char* __restrict__ A,    // [MM2, Kp] fp8 (b-major rows)
    const unsigned char* __restrict__ BT,   // [NMID, Kp] fp8
    const float* __restrict__ bias,         // [NMID]
    unsigned char* __restrict__ Y,          // [MM2, NMID] fp8 (b-major rows)
    int Kp)
{
    __shared__ unsigned char smem[52224];        // max(stage 47104, Zs 52224)
    unsigned char* As = smem;                    // [112][128]
    unsigned char* Bs = smem + 14336;            // [256][128]
    unsigned short* Zs = (unsigned short*)smem;  // [256][ZST] bf16, n-major

    const int tid  = threadIdx.x;
    const int wave = tid >> 6;
    const int lane = tid & 63;

    // XCD swizzle: 32 b's x 4 n-blocks per XCD -> A strips stay L2-local
    const int l   = blockIdx.x;
    const int xcd = l & 7;
    const int p   = l >> 3;                 // 0..127
    const int b   = xcd * 32 + (p >> 2);
    const int bn  = (p & 3) * NBLK;

    const long arow0 = (long)b * TP;

    // hoist tail operands off the critical path (HBM latency hidden under GEMM)
    const float bv = bias[bn + tid];
    unsigned char* yp = Y + arow0 * NMID + bn + tid;

    f32x4 acc[7][4] = {};

    const int srow = tid >> 3;              // 0..31
    const int lch  = tid & 7;
    const int gch  = lch ^ (srow & 7);
    const unsigned char* Aptr = A  + (arow0 + srow) * Kp + gch * 16;
    const unsigned char* Bptr = BT + (long)(bn + srow) * Kp + gch * 16;

    const int mrow = lane & 15;
    const int g    = lane >> 4;             // K-group / n-reg group
    const int wc   = wave * 64;             // wave's column offset

    // Full per-block K-phase rotation (branchless, no runtime division):
    // NT is 7 or 8; p&7 then fold into [0,NT). Spreads resident blocks over
    // all K-phases so only ~1/NT stage at any instant. K-order commutes.
    const int NT = Kp >> 7;
    int roff = p & 7;
    if (roff >= NT) roff -= NT;

    for (int tt = 0; tt < NT; ++tt) {
        int kt = tt + roff;
        if (kt >= NT) kt -= NT;
        const int k0 = kt << 7;

        stage_tile(Aptr, Bptr, As, Bs, srow, lch, Kp, k0);
        __syncthreads();

        int8x bfr[4];
        #pragma unroll
        for (int j = 0; j < 4; ++j) {
            int row = wc + j * 16 + mrow;
            int r7  = row & 7;
            int4x lo = *(const int4x*)&Bs[row * 128 + ((2 * g    ) ^ r7) * 16];
            int4x hi = *(const int4x*)&Bs[row * 128 + ((2 * g + 1) ^ r7) * 16];
            bfr[j][0] = lo[0]; bfr[j][1] = lo[1]; bfr[j][2] = lo[2]; bfr[j][3] = lo[3];
            bfr[j][4] = hi[0]; bfr[j][5] = hi[1]; bfr[j][6] = hi[2]; bfr[j][7] = hi[3];
        }
        #pragma unroll
        for (int i = 0; i < 7; ++i) {
            int row = i * 16 + mrow;
            int r7  = row & 7;
            int4x lo = *(const int4x*)&As[row * 128 + ((2 * g    ) ^ r7) * 16];
            int4x hi = *(const int4x*)&As[row * 128 + ((2 * g + 1) ^ r7) * 16];
            int8x af;
            af[0] = lo[0]; af[1] = lo[1]; af[2] = lo[2]; af[3] = lo[3];
            af[4] = hi[0]; af[5] = hi[1]; af[6] = hi[2]; af[7] = hi[3];
            #pragma unroll
            for (int j = 0; j < 4; ++j)
                acc[i][j] = __builtin_amdgcn_mfma_scale_f32_16x16x128_f8f6f4(
                    bfr[j], af, acc[i][j],
                    0, 0,            // cbsz=fp8 e4m3, blgp=fp8 e4m3
                    0, 0x7F,         // unit scale
                    0, 0x7F);
        }
        __syncthreads();
    }

    // epilogue: acc (lane&15 -> t-in-tile, g*4+reg -> n-in-16) -> Zs[n][t] bf16
    #pragma unroll
    for (int i = 0; i < 7; ++i)
        #pragma unroll
        for (int j = 0; j < 4; ++j) {
            int t  = i * 16 + mrow;
            int nn = wc + j * 16 + g * 4;
            if (t < TT)
                #pragma unroll
                for (int r = 0; r < 4; ++r)
                    Zs[(nn + r) * ZST + t] = f2bf(acc[i][j][r]);
        }
    __syncthreads();

    // recurrence: thread n of 256 walks t sequentially, writes Y fp8.
    // distance-2 prefetched ds_read_b32 (2 bf16/read), conflict-free odd-dword
    // stride; chain carries u = 1-y.
    {
        const unsigned short* zp = Zs + tid * ZST;
        float s = 0.0f, u = 1.0f;            // u = 1 - y
        unsigned int zc = *(const unsigned int*)(zp);        // t 0,1
        unsigned int z1 = *(const unsigned int*)(zp + 2);    // t 2,3
        for (int t0 = 0; t0 < TT; t0 += 2) {
            unsigned int z2 = 0;
            if (t0 + 4 < TT) z2 = *(const unsigned int*)(zp + t0 + 4);
            // t0
            float z = bf2f((unsigned short)(zc & 0xFFFFu));
            s = fmaxf(fmaf(L_TAU * s, u, z), 0.0f);
            u = __builtin_amdgcn_rcpf(1.0f + __expf(s + bv));
            yp[(long)t0 * NMID] = (unsigned char)(__builtin_amdgcn_cvt_pk_fp8_f32(1.0f - u, 0.0f, 0, false) & 0xFF);
            // t0+1
            z = bf2f((unsigned short)(zc >> 16));
            s = fmaxf(fmaf(L_TAU * s, u, z), 0.0f);
            u = __builtin_amdgcn_rcpf(1.0f + __expf(s + bv));
            yp[(long)(t0 + 1) * NMID] = (unsigned char)(__builtin_amdgcn_cvt_pk_fp8_f32(1.0f - u, 0.0f, 0, false) & 0xFF);
            zc = z1; z1 = z2;
        }
    }
}

// ---- Layer 4: GEMM (112x16, K=1024) + recurrence + m, one block per b ------
__global__ __launch_bounds__(256) void layer4_fused(
    const unsigned char* __restrict__ Y3,   // [MM2, NMID] fp8
    const unsigned char* __restrict__ W4T,  // [16][1024] fp8
    const float* __restrict__ b4,
    float* __restrict__ m_out)              // [256][10]
{
    __shared__ float Z4s[TP][N4P];          // 7168 B

    const int tid  = threadIdx.x;
    const int wave = tid >> 6;
    const int lane = tid & 63;
    const int mrow = lane & 15;
    const int g    = lane >> 4;
    const int b    = blockIdx.x;

    // W4 fragments once per wave (same for all row-groups)
    int8x wf[8];
    {
        const unsigned char* wp = W4T + (long)mrow * NMID + g * 32;
        #pragma unroll
        for (int kt = 0; kt < 8; ++kt) {
            int4x wlo = *(const int4x*)(wp + kt * 128);
            int4x whi = *(const int4x*)(wp + kt * 128 + 16);
            wf[kt][0] = wlo[0]; wf[kt][1] = wlo[1]; wf[kt][2] = wlo[2]; wf[kt][3] = wlo[3];
            wf[kt][4] = whi[0]; wf[kt][5] = whi[1]; wf[kt][6] = whi[2]; wf[kt][7] = whi[3];
        }
    }

    for (int rg = wave; rg < 7; rg += 4) {   // 7 row-groups of 16 (112 rows)
        const long row = (long)b * TP + rg * 16 + mrow;
        const unsigned char* ap = Y3 + row * NMID + g * 32;
        f32x4 acc = {};
        #pragma unroll
        for (int kt = 0; kt < 8; ++kt) {
            int4x alo = *(const int4x*)(ap + kt * 128);
            int4x ahi = *(const int4x*)(ap + kt * 128 + 16);
            int8x af;
            af[0] = alo[0]; af[1] = alo[1]; af[2] = alo[2]; af[3] = alo[3];
            af[4] = ahi[0]; af[5] = ahi[1]; af[6] = ahi[2]; af[7] = ahi[3];
            acc = __builtin_amdgcn_mfma_scale_f32_16x16x128_f8f6f4(
                wf[kt], af, acc, 0, 0, 0, 0x7F, 0, 0x7F);
        }
        *(f32x4*)&Z4s[rg * 16 + mrow][g * 4] = acc;
    }
    __syncthreads();

    if (tid < NOUT) {
        const float bv = b4[tid];
        float s = 0.0f, u = 1.0f, msum = 0.0f;
        float zc = Z4s[0][tid];
        float z1 = Z4s[1][tid];
        for (int t = 0; t < TT; ++t) {
            float z2 = (t + 2 < TT) ? Z4s[t + 2][tid] : 0.0f;
            s = fmaxf(fmaf(L_TAU * s, u, zc), 0.0f);
            u = __builtin_amdgcn_rcpf(1.0f + __expf(s + bv));
            msum += 1.0f - u;
            zc = z1; z1 = z2;
        }
        m_out[b * NOUT + tid] = msum;
    }
}

// ---- loss = -mean_b log_softmax(m)[b, y[b]] --------------------------------
__global__ void loss_kernel(const float* __restrict__ m, const int* __restrict__ y,
                            float* __restrict__ out) {
    __shared__ float red[BDIM];
    int b = threadIdx.x;   // 256 threads, 1 block
    float v[NOUT];
    float mx = -1e30f;
    #pragma unroll
    for (int n = 0; n < NOUT; ++n) { v[n] = m[b * NOUT + n]; mx = fmaxf(mx, v[n]); }
    float se = 0.0f;
    #pragma unroll
    for (int n = 0; n < NOUT; ++n) se += __expf(v[n] - mx);
    float lse = mx + __logf(se);
    int lbl = y[b];
    float vy = 0.0f;
    #pragma unroll
    for (int n = 0; n < NOUT; ++n) if (n == lbl) vy = v[n];
    red[b] = -(vy - lse);
    __syncthreads();
    for (int off = 128; off; off >>= 1) {
        if (b < off) red[b] += red[b + off];
        __syncthreads();
    }
    if (b == 0) out[0] = red[0] / (float)BB;
}

extern "C" void kernel_launch(void* const* d_in, const int* in_sizes, int n_in,
                              void* d_out, int out_size, void* d_ws, size_t ws_size,
                              hipStream_t stream) {
    const float* x  = (const float*)d_in[0];
    const int*   y  = (const int*)  d_in[1];
    const float* W1 = (const float*)d_in[2];
    const float* b1 = (const float*)d_in[3];
    const float* W2 = (const float*)d_in[4];
    const float* b2 = (const float*)d_in[5];
    const float* W3 = (const float*)d_in[6];
    const float* b3 = (const float*)d_in[7];
    const float* W4 = (const float*)d_in[8];
    const float* b4 = (const float*)d_in[9];
    float* out = (float*)d_out;

    char* ws = (char*)d_ws;
    size_t off = 0;
    auto alloc = [&](size_t bytes) {
        char* p = ws + off;
        off = (off + bytes + 255) & ~(size_t)255;
        return (void*)p;
    };
    unsigned char* XB  = (unsigned char*)alloc((size_t)MM2 * K1P);
    unsigned char* W1T = (unsigned char*)alloc((size_t)NMID * K1P);
    unsigned char* W2T = (unsigned char*)alloc((size_t)NMID * NMID);
    unsigned char* W3T = (unsigned char*)alloc((size_t)NMID * NMID);
    unsigned char* W4T = (unsigned char*)alloc((size_t)N4P * NMID);
    unsigned char* Ya  = (unsigned char*)alloc((size_t)MM2 * NMID);
    unsigned char* Yb  = (unsigned char*)alloc((size_t)MM2 * NMID);

    // one prep dispatch (all converts independent)
    prep_fused<<<PB_W4, BDIM, 0, stream>>>(x, XB, W1, W1T, W2, W2T, W3, W3T, W4, W4T);

    const int fblocks = BB * (NMID / NBLK);   // 1024
    gemm_snu_fused<<<fblocks, BDIM, 0, stream>>>(XB, W1T, b1, Ya, K1P);
    gemm_snu_fused<<<fblocks, BDIM, 0, stream>>>(Ya, W2T, b2, Yb, NMID);
    gemm_snu_fused<<<fblocks, BDIM, 0, stream>>>(Yb, W3T, b3, Ya, NMID);
    layer4_fused<<<BB, BDIM, 0, stream>>>(Ya, W4T, b4, out + 1);
    loss_kernel<<<1, BDIM, 0, stream>>>(out + 1, y, out);
}